// Round 1
// baseline (100.652 us; speedup 1.0000x reference)
//
#include <hip/hip_runtime.h>
#include <hip/hip_bf16.h>
#include <stdint.h>

#define NGRAPH 64
#define NMAX   512
#define NHEAD  4
// bitmap: NGRAPH * NMAX * NMAX bits = 2 MiB
#define BITMAP_WORDS (NGRAPH * NMAX * (NMAX / 32))   // 8,388,608 bits -> 524,288 words... actually 64*512*16 = 524288
#define BITMAP_BYTES (BITMAP_WORDS * 4)

// ---------------- kernel 1: zero the bitmap ----------------
__global__ void zero_bitmap_kernel(uint4* ws) {
    int tid = blockIdx.x * blockDim.x + threadIdx.x;   // exactly BITMAP_BYTES/16 threads
    ws[tid] = make_uint4(0u, 0u, 0u, 0u);
}

// ---------------- kernel 2: exclusive scan of num_nodes_per_graph ----------------
__global__ void scan_offsets_kernel(const int* __restrict__ nn, int* __restrict__ offs) {
    int t = threadIdx.x;          // 64 threads
    int s = 0;
    for (int k = 0; k < t; ++k) s += nn[k];
    offs[t] = s;
}

// ---------------- kernel 3: edges -> adjacency bitmap ----------------
__global__ void edges_to_bitmap_kernel(const int* __restrict__ ei,
                                       const int* __restrict__ batch,
                                       const int* __restrict__ offs,
                                       uint32_t* __restrict__ bitmap, int E) {
    int e = blockIdx.x * blockDim.x + threadIdx.x;
    if (e >= E) return;
    int src = ei[e];
    int dst = ei[E + e];
    int g   = batch[src];
    int off = offs[g];
    int si  = src - off;
    int di  = dst - off;
    unsigned bitidx = ((unsigned)(g * NMAX + si)) * NMAX + (unsigned)di;
    atomicOr(&bitmap[bitidx >> 5], 1u << (bitidx & 31u));
}

// ---------------- kernel 4: fill output ----------------
// one float4 per thread; total threads = B*H*N*N/4 = 16,777,216
__global__ void fill_out_kernel(const uint32_t* __restrict__ bitmap,
                                const int* __restrict__ nn,
                                const float* __restrict__ W,
                                float4* __restrict__ out4) {
    int tid = blockIdx.x * blockDim.x + threadIdx.x;
    int j4 = tid & 127;          // float4 index within row (j = j4*4)
    int i  = (tid >> 7) & 511;
    int h  = (tid >> 16) & 3;
    int b  = tid >> 18;

    int nb = nn[b];
    float w0 = W[h];             // dist 0 (diagonal)
    float w1 = W[4 + h];         // dist 1 (edge)
    float w6 = W[24 + h];        // dist K+1 (default / invalid)

    int j0 = j4 << 2;
    uint32_t bits = bitmap[((b << 9) + i) * (NMAX / 32) + (j4 >> 3)];

    float4 v;
    float* vp = &v.x;
    bool vi = (i < nb);
#pragma unroll
    for (int k = 0; k < 4; ++k) {
        int j = j0 + k;
        float val = w6;
        if (vi && j < nb) {
            if (j == i) val = w0;
            else if ((bits >> (j & 31)) & 1u) val = w1;
        }
        vp[k] = val;
    }
    out4[tid] = v;
}

// ---------------- fallback path (no workspace): direct writes ----------------
__global__ void fill_default_kernel(const int* __restrict__ nn,  // unused
                                    const float* __restrict__ W,
                                    float4* __restrict__ out4) {
    int tid = blockIdx.x * blockDim.x + threadIdx.x;
    int h = (tid >> 16) & 3;
    float w6 = W[24 + h];
    out4[tid] = make_float4(w6, w6, w6, w6);
}

__global__ void scatter_edges_kernel(const int* __restrict__ ei,
                                     const int* __restrict__ batch,
                                     const int* __restrict__ nn,
                                     const float* __restrict__ W,
                                     float* __restrict__ out, int E) {
    int e = blockIdx.x * blockDim.x + threadIdx.x;
    if (e >= E) return;
    int src = ei[e];
    int dst = ei[E + e];
    int g   = batch[src];
    int off = 0;
    for (int k = 0; k < g; ++k) off += nn[k];   // fallback only
    int si = src - off;
    int di = dst - off;
    if (si == di) return;  // diagonal handled later (dist 0 wins)
#pragma unroll
    for (int h = 0; h < NHEAD; ++h) {
        float w1 = W[4 + h];
        size_t idx = (((size_t)(g * NHEAD + h) * NMAX) + si) * NMAX + di;
        out[idx] = w1;
    }
}

__global__ void diag_kernel(const int* __restrict__ nn,
                            const float* __restrict__ W,
                            float* __restrict__ out) {
    int tid = blockIdx.x * blockDim.x + threadIdx.x;  // B*N threads
    int i = tid & 511;
    int b = tid >> 9;
    if (b >= NGRAPH) return;
    if (i >= nn[b]) return;
#pragma unroll
    for (int h = 0; h < NHEAD; ++h) {
        float w0 = W[h];
        size_t idx = (((size_t)(b * NHEAD + h) * NMAX) + i) * NMAX + i;
        out[idx] = w0;
    }
}

extern "C" void kernel_launch(void* const* d_in, const int* in_sizes, int n_in,
                              void* d_out, int out_size, void* d_ws, size_t ws_size,
                              hipStream_t stream) {
    const int*   ei    = (const int*)d_in[0];
    const int*   batch = (const int*)d_in[1];
    const int*   nn    = (const int*)d_in[2];
    const float* W     = (const float*)d_in[3];
    float* out = (float*)d_out;

    int E = in_sizes[0] / 2;                       // 1,048,576 edges
    int out4_count = out_size / 4;                 // 16,777,216 float4s

    size_t need = (size_t)BITMAP_BYTES + NGRAPH * sizeof(int);
    if (ws_size >= need) {
        uint32_t* bitmap = (uint32_t*)d_ws;
        int* offs = (int*)((char*)d_ws + BITMAP_BYTES);

        int zthreads = BITMAP_BYTES / 16;          // uint4 stores
        zero_bitmap_kernel<<<zthreads / 256, 256, 0, stream>>>((uint4*)d_ws);
        scan_offsets_kernel<<<1, NGRAPH, 0, stream>>>(nn, offs);
        edges_to_bitmap_kernel<<<(E + 255) / 256, 256, 0, stream>>>(ei, batch, offs, bitmap, E);
        fill_out_kernel<<<out4_count / 256, 256, 0, stream>>>(bitmap, nn, W, (float4*)out);
    } else {
        // fallback: direct scatter into output (fill -> edges -> diagonal)
        fill_default_kernel<<<out4_count / 256, 256, 0, stream>>>(nn, W, (float4*)out);
        scatter_edges_kernel<<<(E + 255) / 256, 256, 0, stream>>>(ei, batch, nn, W, out, E);
        diag_kernel<<<(NGRAPH * NMAX) / 256, 256, 0, stream>>>(nn, W, out);
    }
}

// Round 2
// 97.442 us; speedup vs baseline: 1.0330x; 1.0330x over previous
//
#include <hip/hip_runtime.h>
#include <hip/hip_bf16.h>
#include <stdint.h>

#define NGRAPH 64
#define NMAX   512
#define NHEAD  4
// bitmap: NGRAPH * NMAX * NMAX bits = 2 MiB
#define BITMAP_WORDS (NGRAPH * NMAX * (NMAX / 32))
#define BITMAP_BYTES (BITMAP_WORDS * 4)

// ---------------- kernel 1: zero the bitmap ----------------
__global__ void zero_bitmap_kernel(uint4* ws) {
    int tid = blockIdx.x * blockDim.x + threadIdx.x;   // exactly BITMAP_BYTES/16 threads
    ws[tid] = make_uint4(0u, 0u, 0u, 0u);
}

// ---------------- kernel 2: edges -> adjacency bitmap (offsets computed in-block) ----------------
__global__ void edges_to_bitmap_kernel(const int* __restrict__ ei,
                                       const int* __restrict__ batch,
                                       const int* __restrict__ nn,
                                       uint32_t* __restrict__ bitmap, int E) {
    __shared__ int offs[NGRAPH];
    if (threadIdx.x < 64) {
        int v = nn[threadIdx.x];
        int x = v;
#pragma unroll
        for (int d = 1; d < 64; d <<= 1) {
            int y = __shfl_up(x, d, 64);
            if ((threadIdx.x & 63) >= d) x += y;
        }
        offs[threadIdx.x] = x - v;   // exclusive prefix
    }
    __syncthreads();
    int e = blockIdx.x * blockDim.x + threadIdx.x;
    if (e >= E) return;
    int src = ei[e];
    int dst = ei[E + e];
    int g   = batch[src];
    int off = offs[g];
    int si  = src - off;
    int di  = dst - off;
    unsigned bitidx = ((unsigned)(g * NMAX + si)) * NMAX + (unsigned)di;
    atomicOr(&bitmap[bitidx >> 5], 1u << (bitidx & 31u));
}

// ---------------- kernel 3: fill output ----------------
// One wave (64 lanes) = one output row (b,h,i). Each lane writes 32 B:
// j in [lane*4, lane*4+4) and [256+lane*4, 256+lane*4+4).
// Total threads = B*H*N*64 = 8,388,608.
__global__ void fill_out_kernel(const uint32_t* __restrict__ bitmap,
                                const int* __restrict__ nn,
                                const float* __restrict__ W,
                                float4* __restrict__ out4) {
    int tid = blockIdx.x * blockDim.x + threadIdx.x;
    int lane = tid & 63;
    int i = (tid >> 6) & 511;       // wave-uniform
    int h = (tid >> 15) & 3;        // wave-uniform
    int b = tid >> 17;              // wave-uniform
    int nb = nn[b];                 // scalar load

    float w6 = W[24 + h];
    float4 lo = make_float4(w6, w6, w6, w6);
    float4 hi = lo;

    if (i < nb) {                   // wave-uniform branch
        float w1 = W[4 + h];
        float w0 = W[h];
        const uint32_t* row = bitmap + (((b << 9) + i) << 4);   // 16 words per row
        uint32_t blo = row[lane >> 3] >> ((lane & 7) << 2);
        uint32_t bhi = row[8 + (lane >> 3)] >> ((lane & 7) << 2);
        int j0 = lane << 2;
        float* plo = &lo.x;
        float* phi = &hi.x;
#pragma unroll
        for (int k = 0; k < 4; ++k) {
            int j = j0 + k;
            if (j < nb) {
                float v = ((blo >> k) & 1u) ? w1 : w6;
                if (j == i) v = w0;
                plo[k] = v;
            }
            int j2 = 256 + j;
            if (j2 < nb) {
                float v = ((bhi >> k) & 1u) ? w1 : w6;
                if (j2 == i) v = w0;
                phi[k] = v;
            }
        }
    }
    size_t rb = (size_t)(tid >> 6) << 7;    // row id * 128 float4s
    out4[rb + lane]      = lo;              // contiguous 1 KB wave store
    out4[rb + 64 + lane] = hi;              // contiguous 1 KB wave store
}

// ---------------- fallback path (no workspace): direct writes ----------------
__global__ void fill_default_kernel(const float* __restrict__ W,
                                    float4* __restrict__ out4) {
    int tid = blockIdx.x * blockDim.x + threadIdx.x;
    int h = (tid >> 16) & 3;
    float w6 = W[24 + h];
    out4[tid] = make_float4(w6, w6, w6, w6);
}

__global__ void scatter_edges_kernel(const int* __restrict__ ei,
                                     const int* __restrict__ batch,
                                     const int* __restrict__ nn,
                                     const float* __restrict__ W,
                                     float* __restrict__ out, int E) {
    int e = blockIdx.x * blockDim.x + threadIdx.x;
    if (e >= E) return;
    int src = ei[e];
    int dst = ei[E + e];
    int g   = batch[src];
    int off = 0;
    for (int k = 0; k < g; ++k) off += nn[k];
    int si = src - off;
    int di = dst - off;
    if (si == di) return;  // diagonal handled later (dist 0 wins)
#pragma unroll
    for (int h = 0; h < NHEAD; ++h) {
        float w1 = W[4 + h];
        size_t idx = (((size_t)(g * NHEAD + h) * NMAX) + si) * NMAX + di;
        out[idx] = w1;
    }
}

__global__ void diag_kernel(const int* __restrict__ nn,
                            const float* __restrict__ W,
                            float* __restrict__ out) {
    int tid = blockIdx.x * blockDim.x + threadIdx.x;  // B*N threads
    int i = tid & 511;
    int b = tid >> 9;
    if (b >= NGRAPH) return;
    if (i >= nn[b]) return;
#pragma unroll
    for (int h = 0; h < NHEAD; ++h) {
        float w0 = W[h];
        size_t idx = (((size_t)(b * NHEAD + h) * NMAX) + i) * NMAX + i;
        out[idx] = w0;
    }
}

extern "C" void kernel_launch(void* const* d_in, const int* in_sizes, int n_in,
                              void* d_out, int out_size, void* d_ws, size_t ws_size,
                              hipStream_t stream) {
    const int*   ei    = (const int*)d_in[0];
    const int*   batch = (const int*)d_in[1];
    const int*   nn    = (const int*)d_in[2];
    const float* W     = (const float*)d_in[3];
    float* out = (float*)d_out;

    int E = in_sizes[0] / 2;                       // 1,048,576 edges
    int out4_count = out_size / 4;                 // 16,777,216 float4s

    if (ws_size >= (size_t)BITMAP_BYTES) {
        uint32_t* bitmap = (uint32_t*)d_ws;

        int zthreads = BITMAP_BYTES / 16;          // uint4 stores
        zero_bitmap_kernel<<<zthreads / 256, 256, 0, stream>>>((uint4*)d_ws);
        edges_to_bitmap_kernel<<<(E + 255) / 256, 256, 0, stream>>>(ei, batch, nn, bitmap, E);
        int fthreads = out_size / 8;               // 8,388,608 (32 B per thread)
        fill_out_kernel<<<fthreads / 256, 256, 0, stream>>>(bitmap, nn, W, (float4*)out);
    } else {
        // fallback: direct scatter into output (fill -> edges -> diagonal)
        fill_default_kernel<<<out4_count / 256, 256, 0, stream>>>(W, (float4*)out);
        scatter_edges_kernel<<<(E + 255) / 256, 256, 0, stream>>>(ei, batch, nn, W, out, E);
        diag_kernel<<<(NGRAPH * NMAX) / 256, 256, 0, stream>>>(nn, W, out);
    }
}